// Round 9
// baseline (179.893 us; speedup 1.0000x reference)
//
#include <hip/hip_runtime.h>

// PositionNet fused, fp16 MFMA, BARRIER-FREE main loop.
//   K0: w[200][768] fp32 -> ws fp16, fragment-major (344,064 B of d_ws)
//   K1: per-sample fused GEMM + softmax + soft-argmax.
//       512 blocks x 512 threads (8 waves = 2 M-halves x 4 N-groups).
//       A fragments loaded DIRECTLY global->VGPR per lane
//       (addr = ((t*64+kc*32+g*8+e)*64 + mh*32+m_l): 16 consecutive dwords
//       per g-group = 64B-line-exact, 4 lines/instr; 4x ng-redundancy served
//       by L1 since the 16 KB step working set fits 32 KB L1 and all 4
//       consumer waves share the CU). fp32->fp16 cvt in-register.
//       NO LDS staging, NO main-loop barriers -> waves fully decoupled,
//       16 waves/CU of memory-level parallelism. B direct global->VGPR
//       (fragment-major fp16, L2-hot, 1 KiB/frag).
//       Logits (+bias) -> 52 KB LDS hm, ONE barrier, then per-wave
//       softmax(512) + soft-argmax -> d_out.
//
// Numerics identical to round 8 (passed, absmax 0.015625): same RNE
// conversions, same MFMA order. Fragment k-addressing identical for A and B
// (k = kc*32 + g*8 + e), so any HW k-slot permutation cancels; relies only on
// lane&15 = free-dim and the validated C/D layout (col=lane&15,
// row=(lane>>4)*4+reg) from rounds 3-8.

typedef __attribute__((ext_vector_type(4))) float f32x4;
typedef _Float16 f16x8 __attribute__((ext_vector_type(8)));
typedef unsigned short us8 __attribute__((ext_vector_type(8)));

namespace {
constexpr int kB = 512, kC = 768, kP = 64, kO = 200, kJ = 25;
constexpr int kSteps = 12;  // K = 12 steps x 64 channels
constexpr int kNT = 13;     // live 16-wide N tiles (padded to 14 in ws)
constexpr int kHR = 65;     // hm row stride (floats): odd -> spread banks
constexpr int kWsFrag8 = 12 * 2 * 14 * 64;  // 21504 8-elem fragments in ws
constexpr size_t kHmOut = (size_t)kB * kJ * 512;
}  // namespace

// ---- K0: w -> fp16 fragment-major [t*2+kc][nt(14)][lane][e8] ----
__global__ __launch_bounds__(256) void weight_half_kernel(
    const float* __restrict__ w, unsigned short* __restrict__ ws) {
  const int id = blockIdx.x * 256 + threadIdx.x;
  if (id >= kWsFrag8) return;
  const int ml = id & 15, g = (id >> 4) & 3;
  const int id2 = id >> 6;
  const int nt = id2 % 14;
  const int q = id2 / 14;  // q = t*2 + kc
  const int n = nt * 16 + ml;
  const int kb = q * 32 + g * 8;  // t*64 + kc*32 + g*8
  union { _Float16 h[8]; us8 u; } pk;
#pragma unroll
  for (int i = 0; i < 8; ++i) {
    const float v = (n < kO) ? w[(size_t)n * kC + kb + i] : 0.f;
    pk.h[i] = (_Float16)v;  // RNE
  }
  *(us8*)(ws + (size_t)id * 8) = pk.u;  // dst layout == id order
}

__global__ __launch_bounds__(512, 4) void posnet_fused_kernel(
    const float* __restrict__ img, const unsigned short* __restrict__ wsb,
    const float* __restrict__ bias, float* __restrict__ out) {
  __shared__ __align__(16) float hm[kO * kHR];  // 52,000 B; epilogue only

  const int b = blockIdx.x;
  const int tid = threadIdx.x;
  const int lane = tid & 63;
  const int wid = tid >> 6;  // 0..7
  const int ng = __builtin_amdgcn_readfirstlane(wid & 3);   // N-group
  const int mh = __builtin_amdgcn_readfirstlane(wid >> 2);  // M-half
  const int m_l = lane & 15;
  const int g = lane >> 4;

  // Per-lane A base: ((g*8)*64 + mh*32 + m_l); step offset adds
  // (t*64 + kc*32 + e)*64. a1 row = +16 pixels.
  const float* __restrict__ aBase =
      img + (size_t)b * kC * kP + (size_t)(g * 8) * kP + mh * 32 + m_l;

  f32x4 acc[4][2];  // [ni][mt-within-half]
#pragma unroll
  for (int i = 0; i < 4; ++i)
#pragma unroll
    for (int j = 0; j < 2; ++j) acc[i][j] = f32x4{0.f, 0.f, 0.f, 0.f};

  for (int t = 0; t < kSteps; ++t) {
#pragma unroll
    for (int kc = 0; kc < 2; ++kc) {
      // ---- A fragments: 16 line-exact dword loads + in-reg cvt ----
      float a0f[8], a1f[8];
      const float* ap = aBase + (size_t)(t * 64 + kc * 32) * kP;
#pragma unroll
      for (int e = 0; e < 8; ++e) {
        a0f[e] = ap[(size_t)e * kP];
        a1f[e] = ap[(size_t)e * kP + 16];
      }
      union { _Float16 h[8]; f16x8 v; } A0, A1;
#pragma unroll
      for (int e = 0; e < 8; ++e) {
        A0.h[e] = (_Float16)a0f[e];
        A1.h[e] = (_Float16)a1f[e];
      }
      // ---- B fragments + MFMAs ----
#pragma unroll
      for (int ii = 0; ii < 4; ++ii) {
        const int nt = ii * 4 + ng;
        if (nt < kNT) {  // wave-uniform
          const f16x8 bb = *(const f16x8*)(
              wsb + ((size_t)(t * 2 + kc) * 14 + nt) * 512 + lane * 8);
          acc[ii][0] =
              __builtin_amdgcn_mfma_f32_16x16x32_f16(A0.v, bb, acc[ii][0], 0, 0, 0);
          acc[ii][1] =
              __builtin_amdgcn_mfma_f32_16x16x32_f16(A1.v, bb, acc[ii][1], 0, 0, 0);
        }
      }
    }
  }

  // ---- epilogue: logits + bias -> hm LDS ----
#pragma unroll
  for (int ii = 0; ii < 4; ++ii) {
    const int nt = ii * 4 + ng;
    if (nt < kNT) {
      const int o = nt * 16 + m_l;
      if (o < kO) {
        const float bo = bias[o];
#pragma unroll
        for (int mt = 0; mt < 2; ++mt) {
          const int m = (mh * 2 + mt) * 16 + g * 4;
          f32x4 v;
#pragma unroll
          for (int r = 0; r < 4; ++r) v[r] = acc[ii][mt][r] + bo;
          *(f32x4*)(hm + o * kHR + m) = v;
        }
      }
    }
  }
  __syncthreads();  // the ONLY barrier

  // ---- softmax over 512 + soft-argmax; 25 joints over 8 waves ----
  for (int j = wid; j < kJ; j += 8) {
    float v[8];
#pragma unroll
    for (int k = 0; k < 8; ++k) v[k] = hm[(j * 8 + k) * kHR + lane];

    float m = v[0];
#pragma unroll
    for (int k = 1; k < 8; ++k) m = fmaxf(m, v[k]);
#pragma unroll
    for (int off = 32; off > 0; off >>= 1) m = fmaxf(m, __shfl_xor(m, off));

    float e[8];
    float s = 0.f;
#pragma unroll
    for (int k = 0; k < 8; ++k) {
      e[k] = __expf(v[k] - m);
      s += e[k];
    }
#pragma unroll
    for (int off = 32; off > 0; off >>= 1) s += __shfl_xor(s, off);
    const float inv = 1.0f / s;

    float psum = 0.f, zsum = 0.f;
    float* dst = out + ((size_t)b * kJ + j) * 512;
#pragma unroll
    for (int k = 0; k < 8; ++k) {
      const float pv = e[k] * inv;
      dst[k * 64 + lane] = pv;  // coalesced 256 B stores
      psum += pv;
      zsum += (float)k * pv;    // depth index = k
    }
    float xs = (float)(lane & 7) * psum;   // px = h*8+w -> w = lane&7
    float ys = (float)(lane >> 3) * psum;  // h = lane>>3
#pragma unroll
    for (int off = 32; off > 0; off >>= 1) {
      xs += __shfl_xor(xs, off);
      ys += __shfl_xor(ys, off);
      zsum += __shfl_xor(zsum, off);
    }
    if (lane == 0) {
      float* cd = out + kHmOut + ((size_t)b * kJ + j) * 3;
      cd[0] = xs;
      cd[1] = ys;
      cd[2] = zsum;
    }
  }
}

extern "C" void kernel_launch(void* const* d_in, const int* in_sizes, int n_in,
                              void* d_out, int out_size, void* d_ws,
                              size_t ws_size, hipStream_t stream) {
  const float* img = (const float*)d_in[0];     // [512,768,8,8]
  const float* w = (const float*)d_in[1];       // [200,768]
  const float* bias = (const float*)d_in[2];    // [200]
  unsigned short* wsb = (unsigned short*)d_ws;  // 344,064 B used
  float* out = (float*)d_out;

  weight_half_kernel<<<dim3((kWsFrag8 + 255) / 256), dim3(256), 0, stream>>>(w, wsb);
  posnet_fused_kernel<<<dim3(kB), dim3(512), 0, stream>>>(img, wsb, bias, out);
}